// Round 9
// baseline (91.336 us; speedup 1.0000x reference)
//
#include <hip/hip_runtime.h>

#define H   384
#define W   1280
#define PH  192
#define PW  640
#define PP  (PH*PW)      // 122880 pixels per pooled plane
#define LSW 792          // swizzled L row capacity: logical 768 + 24 pads

typedef float f32x4 __attribute__((ext_vector_type(4)));
typedef int   i32x4 __attribute__((ext_vector_type(4)));

// ---------------------------------------------------------------------------
// Kernel A: 2x2 average pool + RGB->YCbCr for both images, both batches.
// Explicit round-to-nearest intrinsics in numpy evaluation order so the
// census '>=' comparisons match the reference bit-for-bit.
// ---------------------------------------------------------------------------
__global__ __launch_bounds__(256) void pool_ycbcr_kernel(
    const float* __restrict__ left, const float* __restrict__ right,
    float* __restrict__ yp, float* __restrict__ cbp, float* __restrict__ crp)
{
    int tid = blockIdx.x * blockDim.x + threadIdx.x;
    if (tid >= 4 * PP) return;
    int p   = tid / PP;
    int rem = tid - p * PP;
    int y   = rem / PW;
    int x   = rem - y * PW;

    const float* src = (p < 2 ? left : right) + (size_t)(p & 1) * 3 * H * W;

    float pc[3];
#pragma unroll
    for (int c = 0; c < 3; ++c) {
        const float* ch = src + (size_t)c * H * W + (size_t)(2 * y) * W + 2 * x;
        float2 a = *(const float2*)ch;
        float2 b = *(const float2*)(ch + W);
        float s = __fadd_rn(__fadd_rn(__fadd_rn(a.x, a.y), b.x), b.y);
        pc[c] = __fmul_rn(s, 0.25f);
    }
    float yv = __fadd_rn(__fadd_rn(__fmul_rn(0.299f, pc[0]),
                                   __fmul_rn(0.587f, pc[1])),
                         __fmul_rn(0.114f, pc[2]));
    float cb = __fadd_rn(__fmul_rn(__fsub_rn(pc[2], yv), 0.564f), 0.5f);
    float cr = __fadd_rn(__fmul_rn(__fsub_rn(pc[0], yv), 0.713f), 0.5f);

    yp[tid]  = yv;
    cbp[tid] = cb;
    crp[tid] = cr;
}

// ---------------------------------------------------------------------------
// Kernel B: 5x5 census transform (24 bits, MSB = offset (0,0)), zero border.
// ---------------------------------------------------------------------------
__global__ __launch_bounds__(256) void census_kernel(
    const float* __restrict__ yp, int* __restrict__ cen)
{
    int tid = blockIdx.x * blockDim.x + threadIdx.x;
    if (tid >= 4 * PP) return;
    int p   = tid / PP;
    int rem = tid - p * PP;
    int y   = rem / PW;
    int x   = rem - y * PW;

    int code = 0;
    if (y >= 2 && y < PH - 2 && x >= 2 && x < PW - 2) {
        const float* base = yp + (size_t)p * PP;
        float c = base[y * PW + x];
        int bit = 23;
#pragma unroll
        for (int v = 0; v < 5; ++v) {
#pragma unroll
            for (int u = 0; u < 5; ++u) {
                if (u == 2 && v == 2) continue;  // center excluded
                float nb = base[(y - 2 + v) * PW + (x - 2 + u)];
                code |= (nb >= c ? 1 : 0) << bit;
                --bit;
            }
        }
    }
    cen[tid] = code;
}

// ---------------------------------------------------------------------------
// Kernel C: cost volume + normalization.
// Block = (n, g, row-pair, d-quarter): stage 2 L-rows (pad-swizzled) and
// 2 R-rows in LDS, emit 32 disparities x 2 consecutive rows.
//  - L swizzle i -> i + (i>>5): staged vec4 writes stay contiguous
//    (4j%32<=28 never crosses a pad); scalar reads Ls[x0+d] spread over
//    all 32 banks (~2-way, free) instead of 8-way conflicts.
//  - Per-d store stream = 2 consecutive rows = 5KB contiguous, walked
//    sequentially (rest = dd*2+row_i ordering) for HBM burst locality.
// ---------------------------------------------------------------------------
__global__ __launch_bounds__(256) void costvol_kernel(
    const float* __restrict__ cbp, const float* __restrict__ crp,
    const int* __restrict__ cen, float* __restrict__ out)
{
    const float m1 = 11.08282948f, i1 = 1.0f / 0.1949711f;
    const float m2 = 0.02175535f,  i2 = 1.0f / 35.91432953f;
    const float m3 = 0.02679042f,  i3 = 1.0f / 26.79782867f;

    int b   = blockIdx.x;           // 2304 blocks
    int n   = b / 1152;
    int r   = b - n * 1152;
    int g   = r / 384;              // block-uniform
    int r2  = r - g * 384;
    int rp  = r2 >> 2;              // row pair 0..95
    int dq  = r2 & 3;               // d quarter: d = dq*32 + dd
    int row0 = rp * 2;
    int d0   = dq * 32;

    __shared__ int Ls[2][LSW];
    __shared__ int Rs[2][640];

    const int* Lplane;
    const int* Rplane;
    if (g == 0)      { Lplane = cen + (size_t)n * PP;
                       Rplane = cen + (size_t)(2 + n) * PP; }
    else if (g == 1) { Lplane = (const int*)(cbp + (size_t)n * PP);
                       Rplane = (const int*)(cbp + (size_t)(2 + n) * PP); }
    else             { Lplane = (const int*)(crp + (size_t)n * PP);
                       Rplane = (const int*)(crp + (size_t)(2 + n) * PP); }

    const int t = threadIdx.x;
    // stage: j in [0,320) -> L rows, [320,640) -> R rows (160 vec4 per row)
    for (int j = t; j < 640; j += 256) {
        if (j < 320) {
            int rr = j / 160;
            int jj = j - rr * 160;
            int o  = jj * 4;
            *(i32x4*)&Ls[rr][o + (o >> 5)] =
                *(const i32x4*)(Lplane + (row0 + rr) * PW + o);
        } else {
            int j2 = j - 320;
            int rr = j2 / 160;
            int jj = j2 - rr * 160;
            *(i32x4*)&Rs[rr][jj * 4] =
                *(const i32x4*)(Rplane + (row0 + rr) * PW + jj * 4);
        }
    }
    __syncthreads();

    // output channel base for this block
    float* outb = out + ((size_t)(n * 384 + g * 128 + d0) * PH + row0) * PW;

    if (g == 0) {
        const float c0 = (0.0f - m1) * i1;
#pragma unroll 4
        for (int k = 0; k < 40; ++k) {
            int idx  = t + 256 * k;        // 0..10239
            int rest = idx / 160;          // 0..63
            int q    = idx - rest * 160;
            int ri   = rest & 1;
            int dd   = rest >> 1;
            int x0   = q * 4;
            int d    = d0 + dd;
            int nvalid = PW - d;
            i32x4 rv = *(const i32x4*)&Rs[ri][x0];
            int i0 = x0 + d, i1_ = i0 + 1, i2_ = i0 + 2, i3_ = i0 + 3;
            int e0 = Ls[ri][i0  + (i0  >> 5)];
            int e1 = Ls[ri][i1_ + (i1_ >> 5)];
            int e2 = Ls[ri][i2_ + (i2_ >> 5)];
            int e3 = Ls[ri][i3_ + (i3_ >> 5)];
            f32x4 ov;
            ov.x = (x0 + 0 < nvalid) ? ((float)__popc(e0 ^ rv.x) - m1) * i1 : c0;
            ov.y = (x0 + 1 < nvalid) ? ((float)__popc(e1 ^ rv.y) - m1) * i1 : c0;
            ov.z = (x0 + 2 < nvalid) ? ((float)__popc(e2 ^ rv.z) - m1) * i1 : c0;
            ov.w = (x0 + 3 < nvalid) ? ((float)__popc(e3 ^ rv.w) - m1) * i1 : c0;
            *(f32x4*)(outb + ((size_t)dd * PH + ri) * PW + x0) = ov;
        }
    } else {
        const float m  = (g == 1) ? m2 : m3;
        const float iv = (g == 1) ? i2 : i3;
        const float c0 = (0.0f - m) * iv;
#pragma unroll 4
        for (int k = 0; k < 40; ++k) {
            int idx  = t + 256 * k;
            int rest = idx / 160;
            int q    = idx - rest * 160;
            int ri   = rest & 1;
            int dd   = rest >> 1;
            int x0   = q * 4;
            int d    = d0 + dd;
            int nvalid = PW - d;
            f32x4 rv = *(const f32x4*)&Rs[ri][x0];
            int i0 = x0 + d, i1_ = i0 + 1, i2_ = i0 + 2, i3_ = i0 + 3;
            const float* Lf = (const float*)Ls[ri];
            float e0 = Lf[i0  + (i0  >> 5)];
            float e1 = Lf[i1_ + (i1_ >> 5)];
            float e2 = Lf[i2_ + (i2_ >> 5)];
            float e3 = Lf[i3_ + (i3_ >> 5)];
            f32x4 ov;
            ov.x = (x0 + 0 < nvalid) ? (fabsf(e0 - rv.x) - m) * iv : c0;
            ov.y = (x0 + 1 < nvalid) ? (fabsf(e1 - rv.y) - m) * iv : c0;
            ov.z = (x0 + 2 < nvalid) ? (fabsf(e2 - rv.z) - m) * iv : c0;
            ov.w = (x0 + 3 < nvalid) ? (fabsf(e3 - rv.w) - m) * iv : c0;
            *(f32x4*)(outb + ((size_t)dd * PH + ri) * PW + x0) = ov;
        }
    }
}

// ---------------------------------------------------------------------------
extern "C" void kernel_launch(void* const* d_in, const int* in_sizes, int n_in,
                              void* d_out, int out_size, void* d_ws, size_t ws_size,
                              hipStream_t stream)
{
    const float* left  = (const float*)d_in[0];
    const float* right = (const float*)d_in[1];

    float* ws  = (float*)d_ws;
    float* yp  = ws;                     // 4 planes of PP floats
    float* cbp = ws + 4 * PP;
    float* crp = ws + 8 * PP;
    int*   cen = (int*)(ws + 12 * PP);   // 4 planes of PP int32

    int threads = 256;
    int blocksAB = (4 * PP + threads - 1) / threads;   // 1920

    pool_ycbcr_kernel<<<blocksAB, threads, 0, stream>>>(left, right, yp, cbp, crp);
    census_kernel<<<blocksAB, threads, 0, stream>>>(yp, cen);

    int blocksC = 2 * 3 * 96 * 4;   // 2304: (n, g, row-pair, d-quarter)
    costvol_kernel<<<blocksC, threads, 0, stream>>>(cbp, crp, cen, (float*)d_out);
}

// Round 11
// 88.356 us; speedup vs baseline: 1.0337x; 1.0337x over previous
//
#include <hip/hip_runtime.h>

#define H   384
#define W   1280
#define PH  192
#define PW  640
#define PP  (PH*PW)      // 122880 pixels per pooled plane

typedef float f32x4 __attribute__((ext_vector_type(4)));
typedef int   i32x4 __attribute__((ext_vector_type(4)));

// ---------------------------------------------------------------------------
// Fused preprocessing: 2x2 avg-pool + RGB->YCbCr + 5x5 census, one kernel.
// Block = (plane p, 64x4 pooled tile). Y computed into LDS with 2-px halo
// (68x8); census reads LDS only; yp never touches global memory.
// CRITICAL: fp contract(off). HIP's __fadd_rn/__fmul_rn are plain ops and
// -ffp-contract=fast may fuse the Y dot-product into FMAs differently per
// kernel context; census '>=' on ~1-ULP-apart values then flips bits vs
// the numpy reference (R10 failure: absmax 5.1875 = one census bit).
// ---------------------------------------------------------------------------
__global__ __launch_bounds__(256) void fused_pre_kernel(
    const float* __restrict__ left, const float* __restrict__ right,
    float* __restrict__ cbp, float* __restrict__ crp, int* __restrict__ cen)
{
#pragma clang fp contract(off)
    // grid: 4 planes x 48 (by) x 10 (bx) = 1920 blocks
    int blk = blockIdx.x;
    int p   = blk / 480;
    int r   = blk - p * 480;
    int by  = r / 10;
    int bx  = r - by * 10;
    int X0  = bx * 64, Y0 = by * 4;

    __shared__ float Ys[8][69];   // 68 cols + 1 pad

    const float* src = (p < 2 ? left : right) + (size_t)(p & 1) * 3 * H * W;
    const int t = threadIdx.x;

    // halo pass: 544 = 68x8 pooled px, threads take 2-3 each
    for (int j = t; j < 544; j += 256) {
        int hy = j / 68;
        int hx = j - hy * 68;
        int gx = X0 - 2 + hx;
        int gy = Y0 - 2 + hy;
        int cx = min(max(gx, 0), PW - 1);   // clamp: OOB values only feed
        int cy = min(max(gy, 0), PH - 1);   // border px whose code=0 anyway

        float pc[3];
#pragma unroll
        for (int c = 0; c < 3; ++c) {
            const float* chp = src + (size_t)c * H * W + (size_t)(2 * cy) * W + 2 * cx;
            float2 a = *(const float2*)chp;
            float2 b = *(const float2*)(chp + W);
            // numpy order: ((x00+x01)+x10)+x11, then *0.25
            float s = ((a.x + a.y) + b.x) + b.y;
            pc[c] = s * 0.25f;
        }
        // y = 0.299*r + 0.587*g + 0.114*b, strict left-to-right, no FMA
        float yv = (0.299f * pc[0] + 0.587f * pc[1]) + 0.114f * pc[2];
        Ys[hy][hx] = yv;

        // tile-interior pixel: also produce cb/cr (each global px exactly once)
        if (hx >= 2 && hx < 66 && hy >= 2 && hy < 6) {
            float cb = (pc[2] - yv) * 0.564f + 0.5f;
            float cr = (pc[0] - yv) * 0.713f + 0.5f;
            size_t o = (size_t)p * PP + (size_t)gy * PW + gx;
            cbp[o] = cb;
            crp[o] = cr;
        }
    }
    __syncthreads();

    // census pass: one px per thread
    int tx = t & 63, ty = t >> 6;
    int gx = X0 + tx, gy = Y0 + ty;
    int code = 0;
    if (gx >= 2 && gx < PW - 2 && gy >= 2 && gy < PH - 2) {
        float c = Ys[ty + 2][tx + 2];
        int bit = 23;
#pragma unroll
        for (int v = 0; v < 5; ++v) {
#pragma unroll
            for (int u = 0; u < 5; ++u) {
                if (u == 2 && v == 2) continue;
                float nb = Ys[ty + v][tx + u];
                code |= (nb >= c ? 1 : 0) << bit;
                --bit;
            }
        }
    }
    cen[(size_t)p * PP + (size_t)gy * PW + gx] = code;
}

// ---------------------------------------------------------------------------
// Kernel C: cost volume + normalization (R6 champion, unchanged).
// Block = (n, g, row, d-half): stage L/R rows in LDS ONCE, emit 64
// disparities from LDS. Plain float4 stores. Measured endpoint: every
// structural variant (NT stores, XCD swizzle, bank-swizzle, burst remap,
// plane-per-block) lands at ~78us => ~5 TB/s effective is this mixed
// pattern's ceiling on gfx950.
// ---------------------------------------------------------------------------
__global__ __launch_bounds__(256) void costvol_kernel(
    const float* __restrict__ cbp, const float* __restrict__ crp,
    const int* __restrict__ cen, float* __restrict__ out)
{
    const float m1 = 11.08282948f, i1 = 1.0f / 0.1949711f;
    const float m2 = 0.02175535f,  i2 = 1.0f / 35.91432953f;
    const float m3 = 0.02679042f,  i3 = 1.0f / 26.79782867f;

    int b   = blockIdx.x;           // 2304 blocks
    int n   = b / 1152;
    int r   = b - n * 1152;
    int g   = r / 384;              // block-uniform
    int r2  = r - g * 384;
    int row = r2 >> 1;
    int dh  = r2 & 1;               // d-half: d = dh*64 + dd

    __shared__ int Ls[776];         // 640 staged + pad for d-overread
    __shared__ int Rs[640];

    const int* Lplane;
    const int* Rplane;
    if (g == 0)      { Lplane = cen + (size_t)n * PP;
                       Rplane = cen + (size_t)(2 + n) * PP; }
    else if (g == 1) { Lplane = (const int*)(cbp + (size_t)n * PP);
                       Rplane = (const int*)(cbp + (size_t)(2 + n) * PP); }
    else             { Lplane = (const int*)(crp + (size_t)n * PP);
                       Rplane = (const int*)(crp + (size_t)(2 + n) * PP); }

    const i32x4* Lg4 = (const i32x4*)(Lplane + row * PW);
    const i32x4* Rg4 = (const i32x4*)(Rplane + row * PW);

    const int t = threadIdx.x;
    for (int j = t; j < 320; j += 256) {
        if (j < 160) *(i32x4*)&Ls[j * 4]         = Lg4[j];
        else         *(i32x4*)&Rs[(j - 160) * 4] = Rg4[j - 160];
    }
    __syncthreads();

    float* outb = out + ((size_t)(n * 384 + g * 128 + dh * 64) * PH + row) * PW;

    if (g == 0) {
        const float c0 = (0.0f - m1) * i1;
#pragma unroll 4
        for (int idx = t; idx < 64 * 160; idx += 256) {
            int dd = idx / 160;            // 0..63
            int q  = idx - dd * 160;
            int x0 = q * 4;
            int d  = dh * 64 + dd;
            int nvalid = PW - d;
            i32x4 rv = *(const i32x4*)&Rs[x0];
            int base = x0 + d;
            int e0 = Ls[base], e1 = Ls[base + 1], e2 = Ls[base + 2], e3 = Ls[base + 3];
            f32x4 ov;
            ov.x = (x0 + 0 < nvalid) ? ((float)__popc(e0 ^ rv.x) - m1) * i1 : c0;
            ov.y = (x0 + 1 < nvalid) ? ((float)__popc(e1 ^ rv.y) - m1) * i1 : c0;
            ov.z = (x0 + 2 < nvalid) ? ((float)__popc(e2 ^ rv.z) - m1) * i1 : c0;
            ov.w = (x0 + 3 < nvalid) ? ((float)__popc(e3 ^ rv.w) - m1) * i1 : c0;
            *(f32x4*)(outb + (size_t)dd * PP + x0) = ov;
        }
    } else {
        const float m  = (g == 1) ? m2 : m3;
        const float iv = (g == 1) ? i2 : i3;
        const float c0 = (0.0f - m) * iv;
        const float* Lf = (const float*)Ls;
        const float* Rf = (const float*)Rs;
#pragma unroll 4
        for (int idx = t; idx < 64 * 160; idx += 256) {
            int dd = idx / 160;
            int q  = idx - dd * 160;
            int x0 = q * 4;
            int d  = dh * 64 + dd;
            int nvalid = PW - d;
            f32x4 rv = *(const f32x4*)&Rf[x0];
            int base = x0 + d;
            float e0 = Lf[base], e1 = Lf[base + 1], e2 = Lf[base + 2], e3 = Lf[base + 3];
            f32x4 ov;
            ov.x = (x0 + 0 < nvalid) ? (fabsf(e0 - rv.x) - m) * iv : c0;
            ov.y = (x0 + 1 < nvalid) ? (fabsf(e1 - rv.y) - m) * iv : c0;
            ov.z = (x0 + 2 < nvalid) ? (fabsf(e2 - rv.z) - m) * iv : c0;
            ov.w = (x0 + 3 < nvalid) ? (fabsf(e3 - rv.w) - m) * iv : c0;
            *(f32x4*)(outb + (size_t)dd * PP + x0) = ov;
        }
    }
}

// ---------------------------------------------------------------------------
extern "C" void kernel_launch(void* const* d_in, const int* in_sizes, int n_in,
                              void* d_out, int out_size, void* d_ws, size_t ws_size,
                              hipStream_t stream)
{
    const float* left  = (const float*)d_in[0];
    const float* right = (const float*)d_in[1];

    float* ws  = (float*)d_ws;
    float* cbp = ws;                     // 4 planes of PP floats
    float* crp = ws + 4 * PP;
    int*   cen = (int*)(ws + 8 * PP);    // 4 planes of PP int32

    int blocksPre = 4 * 48 * 10;         // 1920: (plane, by, bx)
    fused_pre_kernel<<<blocksPre, 256, 0, stream>>>(left, right, cbp, crp, cen);

    int blocksC = 2 * 3 * 192 * 2;       // 2304: (n, g, row, d-half)
    costvol_kernel<<<blocksC, 256, 0, stream>>>(cbp, crp, cen, (float*)d_out);
}